// Round 1
// baseline (4140.571 us; speedup 1.0000x reference)
//
#include <hip/hip_runtime.h>
#include <hip/hip_bf16.h>
#include <cstdint>
#include <cstddef>

#define TT     2048
#define DMODEL 1024
#define NHQ    8
#define HD     128
#define KVD    512
#define WIN    384
#define EPSF   1.1920929e-07f
#define SCALE  0.12f

typedef __attribute__((ext_vector_type(8))) short bf16x8;
typedef __attribute__((ext_vector_type(4))) float f32x4;

__device__ __forceinline__ float b2f(unsigned short u) {
    unsigned int i = ((unsigned int)u) << 16; float f; __builtin_memcpy(&f, &i, 4); return f;
}
__device__ __forceinline__ unsigned short f2b(float f) {
    unsigned int i; __builtin_memcpy(&i, &f, 4);
    unsigned int r = (i + 0x7fffu + ((i >> 16) & 1u)) >> 16;
    return (unsigned short)r;
}

// ---------------------------------------------------------------------------
// Generic GEMM: C[M x Ntot] = A(bf16, M x K) * B(f32->bf16, K x N segments)
// EPI 0: store f32; EPI 1: += f32; EPI 2: relu(x)^2 -> bf16
// ---------------------------------------------------------------------------
template<int EPI>
__global__ __launch_bounds__(256)
void gemm_k(const unsigned short* __restrict__ A, int K,
            const float* __restrict__ B0, int w0,
            const float* __restrict__ B1, int w1,
            const float* __restrict__ B2, int w2,
            void* __restrict__ Cout, int Ntot)
{
    __shared__ unsigned short As[128][40];
    __shared__ unsigned short Bs[128][40];   // Bs[n][k] = B[k][n] (transposed)
    const int tid = threadIdx.x;
    const int m0 = blockIdx.x * 128;
    const int n0 = blockIdx.y * 128;

    const float* B; int Nseg, c0;
    if (n0 < w0)           { B = B0; Nseg = w0; c0 = n0; }
    else if (n0 < w0 + w1) { B = B1; Nseg = w1; c0 = n0 - w0; }
    else                   { B = B2; Nseg = w2; c0 = n0 - w0 - w1; }

    const int lane = tid & 63, wv = tid >> 6;
    const int wr = (wv >> 1) * 64, wc = (wv & 1) * 64;
    const int l15 = lane & 15, lk = (lane >> 4) * 8;
    const int ar = tid >> 2, acg = (tid & 3) * 8;

    f32x4 acc[4][4] = {};

    for (int k0 = 0; k0 < K; k0 += 32) {
        __syncthreads();
        *(uint4*)(&As[ar][acg])      = *(const uint4*)(A + (size_t)(m0 + ar) * K + k0 + acg);
        *(uint4*)(&As[ar + 64][acg]) = *(const uint4*)(A + (size_t)(m0 + ar + 64) * K + k0 + acg);
        #pragma unroll
        for (int i = 0; i < 4; ++i) {
            int idx = tid + i * 256;
            int kr = idx >> 5, nc = (idx & 31) * 4;
            const float4 bv = *(const float4*)(B + (size_t)(k0 + kr) * Nseg + c0 + nc);
            Bs[nc + 0][kr] = f2b(bv.x);
            Bs[nc + 1][kr] = f2b(bv.y);
            Bs[nc + 2][kr] = f2b(bv.z);
            Bs[nc + 3][kr] = f2b(bv.w);
        }
        __syncthreads();
        bf16x8 af[4], bfr[4];
        #pragma unroll
        for (int mi = 0; mi < 4; ++mi) af[mi]  = *(const bf16x8*)(&As[wr + mi * 16 + l15][lk]);
        #pragma unroll
        for (int ni = 0; ni < 4; ++ni) bfr[ni] = *(const bf16x8*)(&Bs[wc + ni * 16 + l15][lk]);
        #pragma unroll
        for (int mi = 0; mi < 4; ++mi)
            #pragma unroll
            for (int ni = 0; ni < 4; ++ni)
                acc[mi][ni] = __builtin_amdgcn_mfma_f32_16x16x32_bf16(af[mi], bfr[ni], acc[mi][ni], 0, 0, 0);
    }

    const int lr4 = (lane >> 4) * 4;
    #pragma unroll
    for (int mi = 0; mi < 4; ++mi)
        #pragma unroll
        for (int ni = 0; ni < 4; ++ni)
            #pragma unroll
            for (int r = 0; r < 4; ++r) {
                int row = m0 + wr + mi * 16 + lr4 + r;
                int col = n0 + wc + ni * 16 + l15;
                size_t idx = (size_t)row * Ntot + col;
                float v = acc[mi][ni][r];
                if (EPI == 0)      ((float*)Cout)[idx] = v;
                else if (EPI == 1) ((float*)Cout)[idx] += v;
                else {
                    float z = v > 0.f ? v * v : 0.f;
                    ((unsigned short*)Cout)[idx] = f2b(z);
                }
            }
}

// ---------------------------------------------------------------------------
// RMSNorm over 1024: h(f32) -> xn(bf16)
// ---------------------------------------------------------------------------
__global__ __launch_bounds__(256)
void rmsnorm_k(const float* __restrict__ h, unsigned short* __restrict__ xn)
{
    const int t = blockIdx.x, tid = threadIdx.x;
    float4 v = *(const float4*)(h + (size_t)t * DMODEL + tid * 4);
    float ss = v.x*v.x + v.y*v.y + v.z*v.z + v.w*v.w;
    #pragma unroll
    for (int m = 1; m < 64; m <<= 1) ss += __shfl_xor(ss, m);
    __shared__ float red[4];
    if ((tid & 63) == 0) red[tid >> 6] = ss;
    __syncthreads();
    float tot = red[0] + red[1] + red[2] + red[3];
    float rs = rsqrtf(tot * (1.f / DMODEL) + EPSF);
    unsigned short o[4] = { f2b(v.x*rs), f2b(v.y*rs), f2b(v.z*rs), f2b(v.w*rs) };
    *(ushort4*)(xn + (size_t)t * DMODEL + tid * 4) = *(const ushort4*)o;
}

// ---------------------------------------------------------------------------
// Post-QKV: rotary + head-RMSNorm on q,k (->bf16); ve-gate + bf16 on v
// qkv layout per token: [q 1024 | k 512 | v 512] (f32)
// ---------------------------------------------------------------------------
__global__ __launch_bounds__(256)
void post_qkv_k(const float* __restrict__ qkv, const unsigned short* __restrict__ xn,
                const float* __restrict__ cosb, const float* __restrict__ sinb,
                const float* __restrict__ Wgate, const float* __restrict__ vel, int hasve,
                unsigned short* __restrict__ qn, unsigned short* __restrict__ kn,
                unsigned short* __restrict__ vn)
{
    const int t = blockIdx.x, tid = threadIdx.x;
    __shared__ float cs[64], sn[64], gate[4];
    if (tid < 64) { cs[tid] = cosb[t * 64 + tid]; sn[tid] = sinb[t * 64 + tid]; }
    if (hasve && tid >= 64 && tid < 68) {
        int g = tid - 64; float a = 0.f;
        for (int c = 0; c < 32; ++c) a += b2f(xn[(size_t)t * DMODEL + c]) * Wgate[c * 4 + g];
        gate[g] = 2.f / (1.f + __expf(-a));
    }
    __syncthreads();
    if (tid < 96) {
        const int hid = tid >> 3, sub = tid & 7;
        const float* src; unsigned short* dst;
        if (hid < 8) { src = qkv + (size_t)t * 2048 + hid * 128;            dst = qn + (size_t)t * 1024 + hid * 128; }
        else         { src = qkv + (size_t)t * 2048 + 1024 + (hid - 8) * 128; dst = kn + (size_t)t * 512 + (hid - 8) * 128; }
        float o1[8], o2[8], ssum = 0.f;
        #pragma unroll
        for (int j = 0; j < 8; ++j) {
            int jj = sub * 8 + j;
            float x1 = src[jj], x2 = src[jj + 64];
            float c = cs[jj], s = sn[jj];
            o1[j] = x1 * c + x2 * s;
            o2[j] = -x1 * s + x2 * c;
            ssum += o1[j]*o1[j] + o2[j]*o2[j];
        }
        ssum += __shfl_xor(ssum, 1); ssum += __shfl_xor(ssum, 2); ssum += __shfl_xor(ssum, 4);
        float rs = rsqrtf(ssum * (1.f / HD) + EPSF);
        #pragma unroll
        for (int j = 0; j < 8; ++j) {
            int jj = sub * 8 + j;
            dst[jj]      = f2b(o1[j] * rs);
            dst[jj + 64] = f2b(o2[j] * rs);
        }
    }
    {
        int d0 = tid * 2;
        #pragma unroll
        for (int j = 0; j < 2; ++j) {
            int d = d0 + j;
            float vv = qkv[(size_t)t * 2048 + 1536 + d];
            if (hasve) vv += gate[d >> 7] * vel[(size_t)t * KVD + d];
            vn[(size_t)t * KVD + d] = f2b(vv);
        }
    }
}

// ---------------------------------------------------------------------------
// Flash attention: 1 wave per 16 q-rows per head; SBLK=32; online softmax.
// ---------------------------------------------------------------------------
__global__ __launch_bounds__(256)
void attn_k(const unsigned short* __restrict__ qn, const unsigned short* __restrict__ kn,
            const unsigned short* __restrict__ vn, unsigned short* __restrict__ y,
            const int* __restrict__ seqlens, int isS)
{
    __shared__ unsigned short Plds[4][16][40];
    const int tid = threadIdx.x, w = tid >> 6, lane = tid & 63;
    const int h = blockIdx.y, hkv = h >> 1;
    const int qr = (blockIdx.x * 4 + w) * 16;
    const int s1 = seqlens[1], s2 = seqlens[2], s3 = seqlens[3];
    const int l15 = lane & 15, lhi = lane >> 4;

    bf16x8 qf[4];
    #pragma unroll
    for (int kk = 0; kk < 4; ++kk)
        qf[kk] = *(const bf16x8*)(qn + (size_t)(qr + l15) * 1024 + h * HD + kk * 32 + lhi * 8);

    int drow[4];
    #pragma unroll
    for (int r = 0; r < 4; ++r) {
        int row = qr + lhi * 4 + r;
        drow[r] = (row >= s1) + (row >= s2) + (row >= s3);
    }
    int dq = (qr >= s1) + (qr >= s2) + (qr >= s3);
    int dstart = dq == 0 ? 0 : (dq == 1 ? s1 : (dq == 2 ? s2 : s3));
    int smin = dstart;
    if (isS) { int wlo = qr - WIN; if (wlo > smin) smin = wlo; }
    if (smin < 0) smin = 0;
    const int smax = qr + 16;

    f32x4 acc[8] = {};
    float mrow[4] = { -1e30f, -1e30f, -1e30f, -1e30f };
    float lrow[4] = { 0.f, 0.f, 0.f, 0.f };

    for (int s0 = smin & ~31; s0 < smax; s0 += 32) {
        float sv[2][4];
        #pragma unroll
        for (int nb = 0; nb < 2; ++nb) {
            f32x4 S = {};
            int scol = s0 + nb * 16 + l15;
            int scl = scol < TT ? scol : TT - 1;
            #pragma unroll
            for (int kk = 0; kk < 4; ++kk) {
                bf16x8 kf = *(const bf16x8*)(kn + (size_t)scl * KVD + hkv * HD + kk * 32 + lhi * 8);
                S = __builtin_amdgcn_mfma_f32_16x16x32_bf16(qf[kk], kf, S, 0, 0, 0);
            }
            int dcol = (scol >= s1) + (scol >= s2) + (scol >= s3);
            #pragma unroll
            for (int r = 0; r < 4; ++r) {
                int row = qr + lhi * 4 + r;
                bool valid = (scol <= row) && (dcol == drow[r]) && (!isS || (row - scol) <= WIN);
                sv[nb][r] = valid ? S[r] * SCALE : -1e30f;
            }
        }
        #pragma unroll
        for (int r = 0; r < 4; ++r) {
            float pm = fmaxf(sv[0][r], sv[1][r]);
            pm = fmaxf(pm, __shfl_xor(pm, 1));
            pm = fmaxf(pm, __shfl_xor(pm, 2));
            pm = fmaxf(pm, __shfl_xor(pm, 4));
            pm = fmaxf(pm, __shfl_xor(pm, 8));
            float mnew = fmaxf(mrow[r], pm);
            float scl2 = __expf(mrow[r] - mnew);
            float p0 = __expf(sv[0][r] - mnew);
            float p1 = __expf(sv[1][r] - mnew);
            float ps = p0 + p1;
            ps += __shfl_xor(ps, 1); ps += __shfl_xor(ps, 2);
            ps += __shfl_xor(ps, 4); ps += __shfl_xor(ps, 8);
            lrow[r] = lrow[r] * scl2 + ps;
            mrow[r] = mnew;
            #pragma unroll
            for (int nb = 0; nb < 8; ++nb) acc[nb][r] *= scl2;
            Plds[w][lhi * 4 + r][l15]      = f2b(p0);
            Plds[w][lhi * 4 + r][16 + l15] = f2b(p1);
        }
        bf16x8 pf = *(const bf16x8*)(&Plds[w][l15][lhi * 8]);
        #pragma unroll
        for (int nb = 0; nb < 8; ++nb) {
            bf16x8 vf;
            #pragma unroll
            for (int j = 0; j < 8; ++j) {
                int srow = s0 + lhi * 8 + j; if (srow > TT - 1) srow = TT - 1;
                ((short*)&vf)[j] = (short)vn[(size_t)srow * KVD + hkv * HD + nb * 16 + l15];
            }
            acc[nb] = __builtin_amdgcn_mfma_f32_16x16x32_bf16(pf, vf, acc[nb], 0, 0, 0);
        }
    }
    #pragma unroll
    for (int r = 0; r < 4; ++r) {
        float inv = 1.f / lrow[r];
        int row = qr + lhi * 4 + r;
        #pragma unroll
        for (int nb = 0; nb < 8; ++nb)
            y[(size_t)row * 1024 + h * HD + nb * 16 + l15] = f2b(acc[nb][r] * inv);
    }
}

// ---------------------------------------------------------------------------
extern "C" void kernel_launch(void* const* d_in, const int* in_sizes, int n_in,
                              void* d_out, int out_size, void* d_ws, size_t ws_size,
                              hipStream_t stream)
{
    const float* x       = (const float*)d_in[0];
    const float* ve      = (const float*)d_in[1];
    const float* Wq      = (const float*)d_in[2];
    const float* Wk      = (const float*)d_in[3];
    const float* Wv      = (const float*)d_in[4];
    const float* Wo      = (const float*)d_in[5];
    const float* Wgate   = (const float*)d_in[6];
    const float* Wfc     = (const float*)d_in[7];
    const float* Wproj   = (const float*)d_in[8];
    const float* cosb    = (const float*)d_in[9];
    const float* sinb    = (const float*)d_in[10];
    const int*   seqlens = (const int*)d_in[11];

    float* h = (float*)d_out;
    char* ws = (char*)d_ws;
    unsigned short* xn   = (unsigned short*)(ws);                 // 4 MB
    float*          qkvf = (float*)(ws + (4ull << 20));           // 16 MB
    unsigned short* qn   = (unsigned short*)(ws + (20ull << 20)); // 4 MB
    unsigned short* kn   = (unsigned short*)(ws + (24ull << 20)); // 2 MB
    unsigned short* vn   = (unsigned short*)(ws + (26ull << 20)); // 2 MB
    unsigned short* yb   = (unsigned short*)(ws + (28ull << 20)); // 4 MB
    unsigned short* mb   = (unsigned short*)(ws + (32ull << 20)); // 16 MB

    hipMemcpyAsync(h, x, (size_t)TT * DMODEL * sizeof(float), hipMemcpyDeviceToDevice, stream);

    for (int l = 0; l < 8; ++l) {
        int hasve = (l % 2) == 1;
        int isS   = (l % 4) != 3;

        rmsnorm_k<<<TT, 256, 0, stream>>>(h, xn);

        gemm_k<0><<<dim3(16, 16), 256, 0, stream>>>(xn, 1024,
            Wq + (size_t)l * 1024 * 1024, 1024,
            Wk + (size_t)l * 1024 * 512,  512,
            Wv + (size_t)l * 1024 * 512,  512,
            qkvf, 2048);

        post_qkv_k<<<TT, 256, 0, stream>>>(qkvf, xn, cosb, sinb,
            Wgate + (size_t)l * 128, ve + (size_t)l * TT * KVD, hasve, qn, kn, vn);

        attn_k<<<dim3(32, 8), 256, 0, stream>>>(qn, kn, vn, yb, seqlens, isS);

        gemm_k<1><<<dim3(16, 8), 256, 0, stream>>>(yb, 1024,
            Wo + (size_t)l * 1024 * 1024, 1024, nullptr, 0, nullptr, 0, h, 1024);

        rmsnorm_k<<<TT, 256, 0, stream>>>(h, xn);

        gemm_k<2><<<dim3(16, 32), 256, 0, stream>>>(xn, 1024,
            Wfc + (size_t)l * 1024 * 4096, 4096, nullptr, 0, nullptr, 0, mb, 4096);

        gemm_k<1><<<dim3(16, 8), 256, 0, stream>>>(mb, 4096,
            Wproj + (size_t)l * 4096 * 1024, 1024, nullptr, 0, nullptr, 0, h, 1024);
    }
}

// Round 2
// 1620.459 us; speedup vs baseline: 2.5552x; 2.5552x over previous
//
#include <hip/hip_runtime.h>
#include <hip/hip_bf16.h>
#include <cstdint>
#include <cstddef>

#define TT     2048
#define DMODEL 1024
#define NHQ    8
#define HD     128
#define KVD    512
#define WIN    384
#define EPSF   1.1920929e-07f
#define SCALE  0.12f

typedef __attribute__((ext_vector_type(8))) short bf16x8;
typedef __attribute__((ext_vector_type(4))) float f32x4;

__device__ __forceinline__ float b2f(unsigned short u) {
    unsigned int i = ((unsigned int)u) << 16; float f; __builtin_memcpy(&f, &i, 4); return f;
}
__device__ __forceinline__ unsigned short f2b(float f) {
    unsigned int i; __builtin_memcpy(&i, &f, 4);
    unsigned int r = (i + 0x7fffu + ((i >> 16) & 1u)) >> 16;
    return (unsigned short)r;
}

__device__ __forceinline__ void gl_lds16(const unsigned short* g, unsigned short* l) {
    __builtin_amdgcn_global_load_lds(
        (const __attribute__((address_space(1))) unsigned int*)g,
        (__attribute__((address_space(3))) unsigned int*)l, 16, 0, 0);
}

// ---------------------------------------------------------------------------
// Per-layer weight convert+transpose: W f32 [K][N] -> Wt bf16 [N][K].
// One launch covers Wq|Wk|Wv (into fused qkv table), Wo, Wfc, Wproj.
// 64x64 tiles, LDS transpose. HBM-bound.
// ---------------------------------------------------------------------------
__global__ __launch_bounds__(256)
void convT_k(const float* __restrict__ Wq, const float* __restrict__ Wk,
             const float* __restrict__ Wv, const float* __restrict__ Wo,
             const float* __restrict__ Wfc, const float* __restrict__ Wproj,
             unsigned short* __restrict__ Bqkv, unsigned short* __restrict__ Bo,
             unsigned short* __restrict__ Bfc, unsigned short* __restrict__ Bproj)
{
    __shared__ unsigned short lt[64][72];
    const int bid = blockIdx.x, tid = threadIdx.x;

    const float* W; unsigned short* Wt; int K, N, t, nbase;
    if (bid < 256)        { W = Wq;    Wt = Bqkv;  K = 1024; N = 1024; t = bid;        nbase = 0;    }
    else if (bid < 384)   { W = Wk;    Wt = Bqkv;  K = 1024; N = 512;  t = bid - 256;  nbase = 1024; }
    else if (bid < 512)   { W = Wv;    Wt = Bqkv;  K = 1024; N = 512;  t = bid - 384;  nbase = 1536; }
    else if (bid < 768)   { W = Wo;    Wt = Bo;    K = 1024; N = 1024; t = bid - 512;  nbase = 0;    }
    else if (bid < 1792)  { W = Wfc;   Wt = Bfc;   K = 1024; N = 4096; t = bid - 768;  nbase = 0;    }
    else                  { W = Wproj; Wt = Bproj; K = 4096; N = 1024; t = bid - 1792; nbase = 0;    }

    const int ktiles = K >> 6;
    const int k0 = (t % ktiles) * 64, n0 = (t / ktiles) * 64;

    #pragma unroll
    for (int i = 0; i < 4; ++i) {
        int row = (tid >> 4) + i * 16;
        int col = (tid & 15) * 4;
        float4 v = *(const float4*)(W + (size_t)(k0 + row) * N + n0 + col);
        lt[col + 0][row] = f2b(v.x);
        lt[col + 1][row] = f2b(v.y);
        lt[col + 2][row] = f2b(v.z);
        lt[col + 3][row] = f2b(v.w);
    }
    __syncthreads();
    #pragma unroll
    for (int i = 0; i < 2; ++i) {
        int c = tid * 2 + i;
        int n = c >> 3, kc = (c & 7) * 8;
        *(uint4*)(Wt + (size_t)(nbase + n0 + n) * K + k0 + kc) = *(const uint4*)(&lt[n][kc]);
    }
}

// ---------------------------------------------------------------------------
// m97-structure GEMM: C[M x Ntot] = A(bf16 [M][K]) * Bt(bf16 [Ntot][K])^T
// 128x128 tile, BK=32, global_load_lds staging, 16x16x32 MFMA.
// EPI 0: store f32 at Cf + z*M*Ntot (split-K partials / plain store)
// EPI 2: relu(x)^2 -> bf16 at Cb
// ---------------------------------------------------------------------------
template<int EPI>
__global__ __launch_bounds__(256)
void gemm2(const unsigned short* __restrict__ A, const unsigned short* __restrict__ Bt,
           float* __restrict__ Cf, unsigned short* __restrict__ Cb,
           int K, int ksplit, int Ntot)
{
    __shared__ unsigned short As[128 * 32];
    __shared__ unsigned short Bs[128 * 32];
    const int tid = threadIdx.x, lane = tid & 63, wv = tid >> 6;
    const int m0 = blockIdx.x * 128, n0 = blockIdx.y * 128;
    const int kbeg = blockIdx.z * ksplit, kend = kbeg + ksplit;

    const int wr = (wv >> 1) * 64, wc = (wv & 1) * 64;
    const int l15 = lane & 15, lk = (lane >> 4) * 8;
    const int srow = lane >> 2, scol = (lane & 3) * 8;   // staging: 4 lanes/row, 16B each

    const unsigned short* gA0 = A  + (size_t)(m0 + wv * 32 + srow) * K + scol;
    const unsigned short* gB0 = Bt + (size_t)(n0 + wv * 32 + srow) * K + scol;
    unsigned short* lA0 = As + (wv * 32) * 32;
    unsigned short* lB0 = Bs + (wv * 32) * 32;

    f32x4 acc[4][4] = {};

    for (int k0 = kbeg; k0 < kend; k0 += 32) {
        __syncthreads();
        gl_lds16(gA0 + k0,              lA0);
        gl_lds16(gA0 + k0 + 16 * K,     lA0 + 16 * 32);
        gl_lds16(gB0 + k0,              lB0);
        gl_lds16(gB0 + k0 + 16 * K,     lB0 + 16 * 32);
        __syncthreads();

        bf16x8 af[4], bfv[4];
        #pragma unroll
        for (int mi = 0; mi < 4; ++mi) af[mi]  = *(const bf16x8*)(As + (wr + mi * 16 + l15) * 32 + lk);
        #pragma unroll
        for (int ni = 0; ni < 4; ++ni) bfv[ni] = *(const bf16x8*)(Bs + (wc + ni * 16 + l15) * 32 + lk);
        #pragma unroll
        for (int mi = 0; mi < 4; ++mi)
            #pragma unroll
            for (int ni = 0; ni < 4; ++ni)
                acc[mi][ni] = __builtin_amdgcn_mfma_f32_16x16x32_bf16(af[mi], bfv[ni], acc[mi][ni], 0, 0, 0);
    }

    const int lr4 = (lane >> 4) * 4;
    float* Cz = Cf + (size_t)blockIdx.z * TT * Ntot;
    #pragma unroll
    for (int mi = 0; mi < 4; ++mi)
        #pragma unroll
        for (int ni = 0; ni < 4; ++ni)
            #pragma unroll
            for (int r = 0; r < 4; ++r) {
                int row = m0 + wr + mi * 16 + lr4 + r;
                int col = n0 + wc + ni * 16 + l15;
                size_t idx = (size_t)row * Ntot + col;
                float v = acc[mi][ni][r];
                if (EPI == 0) Cz[idx] = v;
                else {
                    float z = v > 0.f ? v * v : 0.f;
                    Cb[idx] = f2b(z);
                }
            }
}

// ---------------------------------------------------------------------------
// h += sum_z partial[z]   (2048x1024 f32, float4 vectorized)
// ---------------------------------------------------------------------------
__global__ __launch_bounds__(256)
void reduce_add_k(float* __restrict__ h, const float* __restrict__ part, int nz)
{
    const int i = blockIdx.x * 256 + threadIdx.x;          // float4 index
    float4 a = ((const float4*)part)[i];
    for (int z = 1; z < nz; ++z) {
        float4 p = ((const float4*)part)[i + (size_t)z * (TT * DMODEL / 4)];
        a.x += p.x; a.y += p.y; a.z += p.z; a.w += p.w;
    }
    float4 hv = ((float4*)h)[i];
    hv.x += a.x; hv.y += a.y; hv.z += a.z; hv.w += a.w;
    ((float4*)h)[i] = hv;
}

// ---------------------------------------------------------------------------
// RMSNorm over 1024: h(f32) -> xn(bf16)
// ---------------------------------------------------------------------------
__global__ __launch_bounds__(256)
void rmsnorm_k(const float* __restrict__ h, unsigned short* __restrict__ xn)
{
    const int t = blockIdx.x, tid = threadIdx.x;
    float4 v = *(const float4*)(h + (size_t)t * DMODEL + tid * 4);
    float ss = v.x*v.x + v.y*v.y + v.z*v.z + v.w*v.w;
    #pragma unroll
    for (int m = 1; m < 64; m <<= 1) ss += __shfl_xor(ss, m);
    __shared__ float red[4];
    if ((tid & 63) == 0) red[tid >> 6] = ss;
    __syncthreads();
    float tot = red[0] + red[1] + red[2] + red[3];
    float rs = rsqrtf(tot * (1.f / DMODEL) + EPSF);
    unsigned short o[4] = { f2b(v.x*rs), f2b(v.y*rs), f2b(v.z*rs), f2b(v.w*rs) };
    *(ushort4*)(xn + (size_t)t * DMODEL + tid * 4) = *(const ushort4*)o;
}

// ---------------------------------------------------------------------------
// Post-QKV: rotary + head-RMSNorm on q,k (->bf16); ve-gate + bf16 on v
// qkv layout per token: [q 1024 | k 512 | v 512] (f32)
// ---------------------------------------------------------------------------
__global__ __launch_bounds__(256)
void post_qkv_k(const float* __restrict__ qkv, const unsigned short* __restrict__ xn,
                const float* __restrict__ cosb, const float* __restrict__ sinb,
                const float* __restrict__ Wgate, const float* __restrict__ vel, int hasve,
                unsigned short* __restrict__ qn, unsigned short* __restrict__ kn,
                unsigned short* __restrict__ vn)
{
    const int t = blockIdx.x, tid = threadIdx.x;
    __shared__ float cs[64], sn[64], gate[4];
    if (tid < 64) { cs[tid] = cosb[t * 64 + tid]; sn[tid] = sinb[t * 64 + tid]; }
    if (hasve && tid >= 64 && tid < 68) {
        int g = tid - 64; float a = 0.f;
        for (int c = 0; c < 32; ++c) a += b2f(xn[(size_t)t * DMODEL + c]) * Wgate[c * 4 + g];
        gate[g] = 2.f / (1.f + __expf(-a));
    }
    __syncthreads();
    if (tid < 96) {
        const int hid = tid >> 3, sub = tid & 7;
        const float* src; unsigned short* dst;
        if (hid < 8) { src = qkv + (size_t)t * 2048 + hid * 128;            dst = qn + (size_t)t * 1024 + hid * 128; }
        else         { src = qkv + (size_t)t * 2048 + 1024 + (hid - 8) * 128; dst = kn + (size_t)t * 512 + (hid - 8) * 128; }
        float o1[8], o2[8], ssum = 0.f;
        #pragma unroll
        for (int j = 0; j < 8; ++j) {
            int jj = sub * 8 + j;
            float x1 = src[jj], x2 = src[jj + 64];
            float c = cs[jj], s = sn[jj];
            o1[j] = x1 * c + x2 * s;
            o2[j] = -x1 * s + x2 * c;
            ssum += o1[j]*o1[j] + o2[j]*o2[j];
        }
        ssum += __shfl_xor(ssum, 1); ssum += __shfl_xor(ssum, 2); ssum += __shfl_xor(ssum, 4);
        float rs = rsqrtf(ssum * (1.f / HD) + EPSF);
        #pragma unroll
        for (int j = 0; j < 8; ++j) {
            int jj = sub * 8 + j;
            dst[jj]      = f2b(o1[j] * rs);
            dst[jj + 64] = f2b(o2[j] * rs);
        }
    }
    {
        int d0 = tid * 2;
        #pragma unroll
        for (int j = 0; j < 2; ++j) {
            int d = d0 + j;
            float vv = qkv[(size_t)t * 2048 + 1536 + d];
            if (hasve) vv += gate[d >> 7] * vel[(size_t)t * KVD + d];
            vn[(size_t)t * KVD + d] = f2b(vv);
        }
    }
}

// ---------------------------------------------------------------------------
// Flash attention: 1 wave per 16 q-rows per head; SBLK=32; online softmax.
// ---------------------------------------------------------------------------
__global__ __launch_bounds__(256)
void attn_k(const unsigned short* __restrict__ qn, const unsigned short* __restrict__ kn,
            const unsigned short* __restrict__ vn, unsigned short* __restrict__ y,
            const int* __restrict__ seqlens, int isS)
{
    __shared__ unsigned short Plds[4][16][40];
    const int tid = threadIdx.x, w = tid >> 6, lane = tid & 63;
    const int h = blockIdx.y, hkv = h >> 1;
    const int qr = (blockIdx.x * 4 + w) * 16;
    const int s1 = seqlens[1], s2 = seqlens[2], s3 = seqlens[3];
    const int l15 = lane & 15, lhi = lane >> 4;

    bf16x8 qf[4];
    #pragma unroll
    for (int kk = 0; kk < 4; ++kk)
        qf[kk] = *(const bf16x8*)(qn + (size_t)(qr + l15) * 1024 + h * HD + kk * 32 + lhi * 8);

    int drow[4];
    #pragma unroll
    for (int r = 0; r < 4; ++r) {
        int row = qr + lhi * 4 + r;
        drow[r] = (row >= s1) + (row >= s2) + (row >= s3);
    }
    int dq = (qr >= s1) + (qr >= s2) + (qr >= s3);
    int dstart = dq == 0 ? 0 : (dq == 1 ? s1 : (dq == 2 ? s2 : s3));
    int smin = dstart;
    if (isS) { int wlo = qr - WIN; if (wlo > smin) smin = wlo; }
    if (smin < 0) smin = 0;
    const int smax = qr + 16;

    f32x4 acc[8] = {};
    float mrow[4] = { -1e30f, -1e30f, -1e30f, -1e30f };
    float lrow[4] = { 0.f, 0.f, 0.f, 0.f };

    for (int s0 = smin & ~31; s0 < smax; s0 += 32) {
        float sv[2][4];
        #pragma unroll
        for (int nb = 0; nb < 2; ++nb) {
            f32x4 S = {};
            int scol = s0 + nb * 16 + l15;
            int scl = scol < TT ? scol : TT - 1;
            #pragma unroll
            for (int kk = 0; kk < 4; ++kk) {
                bf16x8 kf = *(const bf16x8*)(kn + (size_t)scl * KVD + hkv * HD + kk * 32 + lhi * 8);
                S = __builtin_amdgcn_mfma_f32_16x16x32_bf16(qf[kk], kf, S, 0, 0, 0);
            }
            int dcol = (scol >= s1) + (scol >= s2) + (scol >= s3);
            #pragma unroll
            for (int r = 0; r < 4; ++r) {
                int row = qr + lhi * 4 + r;
                bool valid = (scol <= row) && (dcol == drow[r]) && (!isS || (row - scol) <= WIN);
                sv[nb][r] = valid ? S[r] * SCALE : -1e30f;
            }
        }
        #pragma unroll
        for (int r = 0; r < 4; ++r) {
            float pm = fmaxf(sv[0][r], sv[1][r]);
            pm = fmaxf(pm, __shfl_xor(pm, 1));
            pm = fmaxf(pm, __shfl_xor(pm, 2));
            pm = fmaxf(pm, __shfl_xor(pm, 4));
            pm = fmaxf(pm, __shfl_xor(pm, 8));
            float mnew = fmaxf(mrow[r], pm);
            float scl2 = __expf(mrow[r] - mnew);
            float p0 = __expf(sv[0][r] - mnew);
            float p1 = __expf(sv[1][r] - mnew);
            float ps = p0 + p1;
            ps += __shfl_xor(ps, 1); ps += __shfl_xor(ps, 2);
            ps += __shfl_xor(ps, 4); ps += __shfl_xor(ps, 8);
            lrow[r] = lrow[r] * scl2 + ps;
            mrow[r] = mnew;
            #pragma unroll
            for (int nb = 0; nb < 8; ++nb) acc[nb][r] *= scl2;
            Plds[w][lhi * 4 + r][l15]      = f2b(p0);
            Plds[w][lhi * 4 + r][16 + l15] = f2b(p1);
        }
        bf16x8 pf = *(const bf16x8*)(&Plds[w][l15][lhi * 8]);
        #pragma unroll
        for (int nb = 0; nb < 8; ++nb) {
            bf16x8 vf;
            #pragma unroll
            for (int j = 0; j < 8; ++j) {
                int srow = s0 + lhi * 8 + j; if (srow > TT - 1) srow = TT - 1;
                ((short*)&vf)[j] = (short)vn[(size_t)srow * KVD + hkv * HD + nb * 16 + l15];
            }
            acc[nb] = __builtin_amdgcn_mfma_f32_16x16x32_bf16(pf, vf, acc[nb], 0, 0, 0);
        }
    }
    #pragma unroll
    for (int r = 0; r < 4; ++r) {
        float inv = 1.f / lrow[r];
        int row = qr + lhi * 4 + r;
        #pragma unroll
        for (int nb = 0; nb < 8; ++nb)
            y[(size_t)row * 1024 + h * HD + nb * 16 + l15] = f2b(acc[nb][r] * inv);
    }
}

// ---------------------------------------------------------------------------
extern "C" void kernel_launch(void* const* d_in, const int* in_sizes, int n_in,
                              void* d_out, int out_size, void* d_ws, size_t ws_size,
                              hipStream_t stream)
{
    const float* x       = (const float*)d_in[0];
    const float* ve      = (const float*)d_in[1];
    const float* Wq      = (const float*)d_in[2];
    const float* Wk      = (const float*)d_in[3];
    const float* Wv      = (const float*)d_in[4];
    const float* Wo      = (const float*)d_in[5];
    const float* Wgate   = (const float*)d_in[6];
    const float* Wfc     = (const float*)d_in[7];
    const float* Wproj   = (const float*)d_in[8];
    const float* cosb    = (const float*)d_in[9];
    const float* sinb    = (const float*)d_in[10];
    const int*   seqlens = (const int*)d_in[11];

    float* h = (float*)d_out;
    char* ws = (char*)d_ws;
    unsigned short* xn    = (unsigned short*)(ws);                 // 4 MB
    float*          qkvf  = (float*)(ws + (4ull << 20));           // 16 MB
    unsigned short* qn    = (unsigned short*)(ws + (20ull << 20)); // 4 MB
    unsigned short* kn    = (unsigned short*)(ws + (24ull << 20)); // 2 MB
    unsigned short* vn    = (unsigned short*)(ws + (26ull << 20)); // 2 MB
    unsigned short* yb    = (unsigned short*)(ws + (28ull << 20)); // 4 MB
    unsigned short* mb    = (unsigned short*)(ws + (32ull << 20)); // 16 MB
    float*          part  = (float*)(ws + (48ull << 20));          // 32 MB
    unsigned short* Bqkv  = (unsigned short*)(ws + (80ull << 20)); // 4 MB
    unsigned short* Bo    = (unsigned short*)(ws + (84ull << 20)); // 2 MB
    unsigned short* Bfc   = (unsigned short*)(ws + (86ull << 20)); // 8 MB
    unsigned short* Bproj = (unsigned short*)(ws + (94ull << 20)); // 8 MB -> 102 MB total

    hipMemcpyAsync(h, x, (size_t)TT * DMODEL * sizeof(float), hipMemcpyDeviceToDevice, stream);

    for (int l = 0; l < 8; ++l) {
        int hasve = (l % 2) == 1;
        int isS   = (l % 4) != 3;

        convT_k<<<2816, 256, 0, stream>>>(
            Wq + (size_t)l * 1024 * 1024, Wk + (size_t)l * 1024 * 512,
            Wv + (size_t)l * 1024 * 512,  Wo + (size_t)l * 1024 * 1024,
            Wfc + (size_t)l * 1024 * 4096, Wproj + (size_t)l * 4096 * 1024,
            Bqkv, Bo, Bfc, Bproj);

        rmsnorm_k<<<TT, 256, 0, stream>>>(h, xn);

        gemm2<0><<<dim3(16, 16, 1), 256, 0, stream>>>(xn, Bqkv, qkvf, nullptr, 1024, 1024, 2048);

        post_qkv_k<<<TT, 256, 0, stream>>>(qkvf, xn, cosb, sinb,
            Wgate + (size_t)l * 128, ve + (size_t)l * TT * KVD, hasve, qn, kn, vn);

        attn_k<<<dim3(32, 8), 256, 0, stream>>>(qn, kn, vn, yb, seqlens, isS);

        gemm2<0><<<dim3(16, 8, 2), 256, 0, stream>>>(yb, Bo, part, nullptr, 1024, 512, 1024);
        reduce_add_k<<<2048, 256, 0, stream>>>(h, part, 2);

        rmsnorm_k<<<TT, 256, 0, stream>>>(h, xn);

        gemm2<2><<<dim3(16, 32, 1), 256, 0, stream>>>(xn, Bfc, nullptr, mb, 1024, 1024, 4096);

        gemm2<0><<<dim3(16, 8, 4), 256, 0, stream>>>(mb, Bproj, part, nullptr, 4096, 1024, 1024);
        reduce_add_k<<<2048, 256, 0, stream>>>(h, part, 4);
    }
}

// Round 3
// 1612.972 us; speedup vs baseline: 2.5670x; 1.0046x over previous
//
#include <hip/hip_runtime.h>
#include <hip/hip_bf16.h>
#include <cstdint>
#include <cstddef>

#define TT     2048
#define DMODEL 1024
#define NHQ    8
#define HD     128
#define KVD    512
#define WIN    384
#define EPSF   1.1920929e-07f
#define SCALE  0.12f

typedef __attribute__((ext_vector_type(8))) short bf16x8;
typedef __attribute__((ext_vector_type(4))) float f32x4;

__device__ __forceinline__ float b2f(unsigned short u) {
    unsigned int i = ((unsigned int)u) << 16; float f; __builtin_memcpy(&f, &i, 4); return f;
}
__device__ __forceinline__ unsigned short f2b(float f) {
    unsigned int i; __builtin_memcpy(&i, &f, 4);
    unsigned int r = (i + 0x7fffu + ((i >> 16) & 1u)) >> 16;
    return (unsigned short)r;
}

__device__ __forceinline__ void gl_lds16(const unsigned short* g, unsigned short* l) {
    __builtin_amdgcn_global_load_lds(
        (const __attribute__((address_space(1))) unsigned int*)g,
        (__attribute__((address_space(3))) unsigned int*)l, 16, 0, 0);
}

// ---------------------------------------------------------------------------
// Weight convert+transpose for ALL layers: W f32 [K][N] -> Wt bf16 [N][K].
// grid = (2816, 8); blockIdx.y = layer.
// ---------------------------------------------------------------------------
__global__ __launch_bounds__(256)
void convT_k(const float* __restrict__ Wq, const float* __restrict__ Wk,
             const float* __restrict__ Wv, const float* __restrict__ Wo,
             const float* __restrict__ Wfc, const float* __restrict__ Wproj,
             unsigned short* __restrict__ Bqkv, unsigned short* __restrict__ Bo,
             unsigned short* __restrict__ Bfc, unsigned short* __restrict__ Bproj)
{
    __shared__ unsigned short lt[64][72];
    const int bid = blockIdx.x, tid = threadIdx.x, l = blockIdx.y;

    const float* W; unsigned short* Wt; int K, N, t, nbase;
    if (bid < 256)        { W = Wq    + (size_t)l * 1024 * 1024; Wt = Bqkv  + (size_t)l * 2048 * 1024; K = 1024; N = 1024; t = bid;        nbase = 0;    }
    else if (bid < 384)   { W = Wk    + (size_t)l * 1024 * 512;  Wt = Bqkv  + (size_t)l * 2048 * 1024; K = 1024; N = 512;  t = bid - 256;  nbase = 1024; }
    else if (bid < 512)   { W = Wv    + (size_t)l * 1024 * 512;  Wt = Bqkv  + (size_t)l * 2048 * 1024; K = 1024; N = 512;  t = bid - 384;  nbase = 1536; }
    else if (bid < 768)   { W = Wo    + (size_t)l * 1024 * 1024; Wt = Bo    + (size_t)l * 1024 * 1024; K = 1024; N = 1024; t = bid - 512;  nbase = 0;    }
    else if (bid < 1792)  { W = Wfc   + (size_t)l * 1024 * 4096; Wt = Bfc   + (size_t)l * 4096 * 1024; K = 1024; N = 4096; t = bid - 768;  nbase = 0;    }
    else                  { W = Wproj + (size_t)l * 4096 * 1024; Wt = Bproj + (size_t)l * 1024 * 4096; K = 4096; N = 1024; t = bid - 1792; nbase = 0;    }

    const int ktiles = K >> 6;
    const int k0 = (t % ktiles) * 64, n0 = (t / ktiles) * 64;

    #pragma unroll
    for (int i = 0; i < 4; ++i) {
        int row = (tid >> 4) + i * 16;
        int col = (tid & 15) * 4;
        float4 v = *(const float4*)(W + (size_t)(k0 + row) * N + n0 + col);
        lt[col + 0][row] = f2b(v.x);
        lt[col + 1][row] = f2b(v.y);
        lt[col + 2][row] = f2b(v.z);
        lt[col + 3][row] = f2b(v.w);
    }
    __syncthreads();
    #pragma unroll
    for (int i = 0; i < 2; ++i) {
        int c = tid * 2 + i;
        int n = c >> 3, kc = (c & 7) * 8;
        *(uint4*)(Wt + (size_t)(nbase + n0 + n) * K + k0 + kc) = *(const uint4*)(&lt[n][kc]);
    }
}

// ---------------------------------------------------------------------------
// 2-phase double-buffered GEMM: C = A(bf16 [M][K]) * Bt(bf16 [Ntot][K])^T
// 128x128 tile, BK=32. Prefetch next k-tile via global_load_lds while
// computing current (T3-minimum). One barrier per k-step.
// EPI 0: store f32 at Cf + z*TT*Ntot; EPI 2: relu^2 -> bf16 at Cb.
// ---------------------------------------------------------------------------
template<int EPI>
__global__ __launch_bounds__(256)
void gemm2(const unsigned short* __restrict__ A, const unsigned short* __restrict__ Bt,
           float* __restrict__ Cf, unsigned short* __restrict__ Cb,
           int K, int ksplit, int Ntot)
{
    __shared__ unsigned short As[2 * 128 * 32];
    __shared__ unsigned short Bs[2 * 128 * 32];
    const int BUF = 128 * 32;
    const int tid = threadIdx.x, lane = tid & 63, wv = tid >> 6;
    const int m0 = blockIdx.x * 128, n0 = blockIdx.y * 128;
    const int kbeg = blockIdx.z * ksplit, kend = kbeg + ksplit;

    const int wr = (wv >> 1) * 64, wc = (wv & 1) * 64;
    const int l15 = lane & 15, lk = (lane >> 4) * 8;
    const int srow = lane >> 2, scol = (lane & 3) * 8;

    const unsigned short* gA0 = A  + (size_t)(m0 + wv * 32 + srow) * K + scol;
    const unsigned short* gB0 = Bt + (size_t)(n0 + wv * 32 + srow) * K + scol;
    unsigned short* lA0 = As + (wv * 32) * 32;
    unsigned short* lB0 = Bs + (wv * 32) * 32;

    f32x4 acc[4][4] = {};

    // prologue: stage first tile into buffer 0
    gl_lds16(gA0 + kbeg,          lA0);
    gl_lds16(gA0 + kbeg + 16 * K, lA0 + 16 * 32);
    gl_lds16(gB0 + kbeg,          lB0);
    gl_lds16(gB0 + kbeg + 16 * K, lB0 + 16 * 32);
    __syncthreads();

    int cur = 0;
    for (int k0 = kbeg; k0 < kend; k0 += 32) {
        const int nxt = cur ^ 1;
        if (k0 + 32 < kend) {
            gl_lds16(gA0 + k0 + 32,          lA0 + nxt * BUF);
            gl_lds16(gA0 + k0 + 32 + 16 * K, lA0 + nxt * BUF + 16 * 32);
            gl_lds16(gB0 + k0 + 32,          lB0 + nxt * BUF);
            gl_lds16(gB0 + k0 + 32 + 16 * K, lB0 + nxt * BUF + 16 * 32);
        }
        const unsigned short* Ac = As + cur * BUF;
        const unsigned short* Bc = Bs + cur * BUF;
        bf16x8 af[4], bfv[4];
        #pragma unroll
        for (int mi = 0; mi < 4; ++mi) af[mi]  = *(const bf16x8*)(Ac + (wr + mi * 16 + l15) * 32 + lk);
        #pragma unroll
        for (int ni = 0; ni < 4; ++ni) bfv[ni] = *(const bf16x8*)(Bc + (wc + ni * 16 + l15) * 32 + lk);
        #pragma unroll
        for (int mi = 0; mi < 4; ++mi)
            #pragma unroll
            for (int ni = 0; ni < 4; ++ni)
                acc[mi][ni] = __builtin_amdgcn_mfma_f32_16x16x32_bf16(af[mi], bfv[ni], acc[mi][ni], 0, 0, 0);
        __syncthreads();   // drains vmcnt(0): next tile staged; lgkm done
        cur = nxt;
    }

    const int lr4 = (lane >> 4) * 4;
    float* Cz = Cf + (size_t)blockIdx.z * TT * Ntot;
    #pragma unroll
    for (int mi = 0; mi < 4; ++mi)
        #pragma unroll
        for (int ni = 0; ni < 4; ++ni)
            #pragma unroll
            for (int r = 0; r < 4; ++r) {
                int row = m0 + wr + mi * 16 + lr4 + r;
                int col = n0 + wc + ni * 16 + l15;
                size_t idx = (size_t)row * Ntot + col;
                float v = acc[mi][ni][r];
                if (EPI == 0) Cz[idx] = v;
                else {
                    float z = v > 0.f ? v * v : 0.f;
                    Cb[idx] = f2b(z);
                }
            }
}

// ---------------------------------------------------------------------------
__global__ __launch_bounds__(256)
void reduce_add_k(float* __restrict__ h, const float* __restrict__ part, int nz)
{
    const int i = blockIdx.x * 256 + threadIdx.x;
    float4 a = ((const float4*)part)[i];
    for (int z = 1; z < nz; ++z) {
        float4 p = ((const float4*)part)[i + (size_t)z * (TT * DMODEL / 4)];
        a.x += p.x; a.y += p.y; a.z += p.z; a.w += p.w;
    }
    float4 hv = ((float4*)h)[i];
    hv.x += a.x; hv.y += a.y; hv.z += a.z; hv.w += a.w;
    ((float4*)h)[i] = hv;
}

// ---------------------------------------------------------------------------
__global__ __launch_bounds__(256)
void rmsnorm_k(const float* __restrict__ h, unsigned short* __restrict__ xn)
{
    const int t = blockIdx.x, tid = threadIdx.x;
    float4 v = *(const float4*)(h + (size_t)t * DMODEL + tid * 4);
    float ss = v.x*v.x + v.y*v.y + v.z*v.z + v.w*v.w;
    #pragma unroll
    for (int m = 1; m < 64; m <<= 1) ss += __shfl_xor(ss, m);
    __shared__ float red[4];
    if ((tid & 63) == 0) red[tid >> 6] = ss;
    __syncthreads();
    float tot = red[0] + red[1] + red[2] + red[3];
    float rs = rsqrtf(tot * (1.f / DMODEL) + EPSF);
    unsigned short o[4] = { f2b(v.x*rs), f2b(v.y*rs), f2b(v.z*rs), f2b(v.w*rs) };
    *(ushort4*)(xn + (size_t)t * DMODEL + tid * 4) = *(const ushort4*)o;
}

// ---------------------------------------------------------------------------
// Post-QKV: rotary + head-RMSNorm on q,k (->bf16); ve-gate + bf16 on v (row-major)
// ---------------------------------------------------------------------------
__global__ __launch_bounds__(256)
void post_qkv_k(const float* __restrict__ qkv, const unsigned short* __restrict__ xn,
                const float* __restrict__ cosb, const float* __restrict__ sinb,
                const float* __restrict__ Wgate, const float* __restrict__ vel, int hasve,
                unsigned short* __restrict__ qn, unsigned short* __restrict__ kn,
                unsigned short* __restrict__ vrow)
{
    const int t = blockIdx.x, tid = threadIdx.x;
    __shared__ float cs[64], sn[64], gate[4];
    if (tid < 64) { cs[tid] = cosb[t * 64 + tid]; sn[tid] = sinb[t * 64 + tid]; }
    if (hasve && tid >= 64 && tid < 68) {
        int g = tid - 64; float a = 0.f;
        for (int c = 0; c < 32; ++c) a += b2f(xn[(size_t)t * DMODEL + c]) * Wgate[c * 4 + g];
        gate[g] = 2.f / (1.f + __expf(-a));
    }
    __syncthreads();
    if (tid < 96) {
        const int hid = tid >> 3, sub = tid & 7;
        const float* src; unsigned short* dst;
        if (hid < 8) { src = qkv + (size_t)t * 2048 + hid * 128;              dst = qn + (size_t)t * 1024 + hid * 128; }
        else         { src = qkv + (size_t)t * 2048 + 1024 + (hid - 8) * 128; dst = kn + (size_t)t * 512 + (hid - 8) * 128; }
        float o1[8], o2[8], ssum = 0.f;
        #pragma unroll
        for (int j = 0; j < 8; ++j) {
            int jj = sub * 8 + j;
            float x1 = src[jj], x2 = src[jj + 64];
            float c = cs[jj], s = sn[jj];
            o1[j] = x1 * c + x2 * s;
            o2[j] = -x1 * s + x2 * c;
            ssum += o1[j]*o1[j] + o2[j]*o2[j];
        }
        ssum += __shfl_xor(ssum, 1); ssum += __shfl_xor(ssum, 2); ssum += __shfl_xor(ssum, 4);
        float rs = rsqrtf(ssum * (1.f / HD) + EPSF);
        #pragma unroll
        for (int j = 0; j < 8; ++j) {
            int jj = sub * 8 + j;
            dst[jj]      = f2b(o1[j] * rs);
            dst[jj + 64] = f2b(o2[j] * rs);
        }
    }
    {
        int d0 = tid * 2;
        #pragma unroll
        for (int j = 0; j < 2; ++j) {
            int d = d0 + j;
            float vv = qkv[(size_t)t * 2048 + 1536 + d];
            if (hasve) vv += gate[d >> 7] * vel[(size_t)t * KVD + d];
            vrow[(size_t)t * KVD + d] = f2b(vv);
        }
    }
}

// ---------------------------------------------------------------------------
// vrow [T][KVD] -> vt [KVD][T]  (64x64 LDS tile transpose)
// ---------------------------------------------------------------------------
__global__ __launch_bounds__(256)
void vtrans_k(const unsigned short* __restrict__ vrow, unsigned short* __restrict__ vt)
{
    __shared__ unsigned short lt[64][72];
    const int t0 = blockIdx.x * 64, c0 = blockIdx.y * 64, tid = threadIdx.x;
    #pragma unroll
    for (int i = 0; i < 2; ++i) {
        int r = (tid >> 3) + i * 32;
        int c = (tid & 7) * 8;
        bf16x8 v = *(const bf16x8*)(vrow + (size_t)(t0 + r) * KVD + c0 + c);
        #pragma unroll
        for (int j = 0; j < 8; ++j) lt[c + j][r] = ((unsigned short*)&v)[j];
    }
    __syncthreads();
    #pragma unroll
    for (int i = 0; i < 2; ++i) {
        int r = (tid >> 3) + i * 32;
        int c = (tid & 7) * 8;
        *(bf16x8*)(vt + (size_t)(c0 + r) * TT + t0 + c) = *(const bf16x8*)(&lt[r][c]);
    }
}

// ---------------------------------------------------------------------------
// Flash attention: 1 wave per 16 q-rows per head; SBLK=32; online softmax.
// V consumed from transposed vt[kvh*HD + d][t] -> vector B-fragments.
// ---------------------------------------------------------------------------
__global__ __launch_bounds__(256)
void attn_k(const unsigned short* __restrict__ qn, const unsigned short* __restrict__ kn,
            const unsigned short* __restrict__ vt, unsigned short* __restrict__ y,
            const int* __restrict__ seqlens, int isS)
{
    __shared__ unsigned short Plds[4][16][40];
    const int tid = threadIdx.x, w = tid >> 6, lane = tid & 63;
    const int h = blockIdx.y, hkv = h >> 1;
    const int qr = (blockIdx.x * 4 + w) * 16;
    const int s1 = seqlens[1], s2 = seqlens[2], s3 = seqlens[3];
    const int l15 = lane & 15, lhi = lane >> 4;

    bf16x8 qf[4];
    #pragma unroll
    for (int kk = 0; kk < 4; ++kk)
        qf[kk] = *(const bf16x8*)(qn + (size_t)(qr + l15) * 1024 + h * HD + kk * 32 + lhi * 8);

    int drow[4];
    #pragma unroll
    for (int r = 0; r < 4; ++r) {
        int row = qr + lhi * 4 + r;
        drow[r] = (row >= s1) + (row >= s2) + (row >= s3);
    }
    int dq = (qr >= s1) + (qr >= s2) + (qr >= s3);
    int dstart = dq == 0 ? 0 : (dq == 1 ? s1 : (dq == 2 ? s2 : s3));
    int smin = dstart;
    if (isS) { int wlo = qr - WIN; if (wlo > smin) smin = wlo; }
    if (smin < 0) smin = 0;
    const int smax = qr + 16;

    f32x4 acc[8] = {};
    float mrow[4] = { -1e30f, -1e30f, -1e30f, -1e30f };
    float lrow[4] = { 0.f, 0.f, 0.f, 0.f };

    for (int s0 = smin & ~31; s0 < smax; s0 += 32) {
        float sv[2][4];
        #pragma unroll
        for (int nb = 0; nb < 2; ++nb) {
            f32x4 S = {};
            int scol = s0 + nb * 16 + l15;
            int scl = scol < TT ? scol : TT - 1;
            #pragma unroll
            for (int kk = 0; kk < 4; ++kk) {
                bf16x8 kf = *(const bf16x8*)(kn + (size_t)scl * KVD + hkv * HD + kk * 32 + lhi * 8);
                S = __builtin_amdgcn_mfma_f32_16x16x32_bf16(qf[kk], kf, S, 0, 0, 0);
            }
            int dcol = (scol >= s1) + (scol >= s2) + (scol >= s3);
            #pragma unroll
            for (int r = 0; r < 4; ++r) {
                int row = qr + lhi * 4 + r;
                bool valid = (scol <= row) && (dcol == drow[r]) && (!isS || (row - scol) <= WIN);
                sv[nb][r] = valid ? S[r] * SCALE : -1e30f;
            }
        }
        #pragma unroll
        for (int r = 0; r < 4; ++r) {
            float pm = fmaxf(sv[0][r], sv[1][r]);
            pm = fmaxf(pm, __shfl_xor(pm, 1));
            pm = fmaxf(pm, __shfl_xor(pm, 2));
            pm = fmaxf(pm, __shfl_xor(pm, 4));
            pm = fmaxf(pm, __shfl_xor(pm, 8));
            float mnew = fmaxf(mrow[r], pm);
            float scl2 = __expf(mrow[r] - mnew);
            float p0 = __expf(sv[0][r] - mnew);
            float p1 = __expf(sv[1][r] - mnew);
            float ps = p0 + p1;
            ps += __shfl_xor(ps, 1); ps += __shfl_xor(ps, 2);
            ps += __shfl_xor(ps, 4); ps += __shfl_xor(ps, 8);
            lrow[r] = lrow[r] * scl2 + ps;
            mrow[r] = mnew;
            #pragma unroll
            for (int nb = 0; nb < 8; ++nb) acc[nb][r] *= scl2;
            Plds[w][lhi * 4 + r][l15]      = f2b(p0);
            Plds[w][lhi * 4 + r][16 + l15] = f2b(p1);
        }
        bf16x8 pf = *(const bf16x8*)(&Plds[w][l15][lhi * 8]);
        #pragma unroll
        for (int nb = 0; nb < 8; ++nb) {
            bf16x8 vf = *(const bf16x8*)(vt + (size_t)(hkv * HD + nb * 16 + l15) * TT + s0 + lhi * 8);
            acc[nb] = __builtin_amdgcn_mfma_f32_16x16x32_bf16(pf, vf, acc[nb], 0, 0, 0);
        }
    }
    #pragma unroll
    for (int r = 0; r < 4; ++r) {
        float inv = 1.f / lrow[r];
        int row = qr + lhi * 4 + r;
        #pragma unroll
        for (int nb = 0; nb < 8; ++nb)
            y[(size_t)row * 1024 + h * HD + nb * 16 + l15] = f2b(acc[nb][r] * inv);
    }
}

// ---------------------------------------------------------------------------
extern "C" void kernel_launch(void* const* d_in, const int* in_sizes, int n_in,
                              void* d_out, int out_size, void* d_ws, size_t ws_size,
                              hipStream_t stream)
{
    const float* x       = (const float*)d_in[0];
    const float* ve      = (const float*)d_in[1];
    const float* Wq      = (const float*)d_in[2];
    const float* Wk      = (const float*)d_in[3];
    const float* Wv      = (const float*)d_in[4];
    const float* Wo      = (const float*)d_in[5];
    const float* Wgate   = (const float*)d_in[6];
    const float* Wfc     = (const float*)d_in[7];
    const float* Wproj   = (const float*)d_in[8];
    const float* cosb    = (const float*)d_in[9];
    const float* sinb    = (const float*)d_in[10];
    const int*   seqlens = (const int*)d_in[11];

    float* h = (float*)d_out;
    char* ws = (char*)d_ws;
    unsigned short* xn    = (unsigned short*)(ws);                  // 4 MB
    float*          qkvf  = (float*)(ws + (4ull << 20));            // 16 MB
    unsigned short* qn    = (unsigned short*)(ws + (20ull << 20));  // 4 MB
    unsigned short* kn    = (unsigned short*)(ws + (24ull << 20));  // 2 MB
    unsigned short* vrow  = (unsigned short*)(ws + (26ull << 20));  // 2 MB
    unsigned short* vt    = (unsigned short*)(ws + (28ull << 20));  // 2 MB
    unsigned short* yb    = (unsigned short*)(ws + (30ull << 20));  // 4 MB
    unsigned short* mb    = (unsigned short*)(ws + (34ull << 20));  // 16 MB
    float*          part  = (float*)(ws + (50ull << 20));           // 32 MB
    unsigned short* Bqkv  = (unsigned short*)(ws + (82ull << 20));  // 32 MB (8 layers)
    unsigned short* Bo    = (unsigned short*)(ws + (114ull << 20)); // 16 MB
    unsigned short* Bfc   = (unsigned short*)(ws + (130ull << 20)); // 64 MB
    unsigned short* Bproj = (unsigned short*)(ws + (194ull << 20)); // 64 MB -> 258 MB

    hipMemcpyAsync(h, x, (size_t)TT * DMODEL * sizeof(float), hipMemcpyDeviceToDevice, stream);

    convT_k<<<dim3(2816, 8), 256, 0, stream>>>(Wq, Wk, Wv, Wo, Wfc, Wproj,
                                               Bqkv, Bo, Bfc, Bproj);

    for (int l = 0; l < 8; ++l) {
        int hasve = (l % 2) == 1;
        int isS   = (l % 4) != 3;

        rmsnorm_k<<<TT, 256, 0, stream>>>(h, xn);

        gemm2<0><<<dim3(16, 16, 1), 256, 0, stream>>>(xn, Bqkv + (size_t)l * 2048 * 1024,
                                                      qkvf, nullptr, 1024, 1024, 2048);

        post_qkv_k<<<TT, 256, 0, stream>>>(qkvf, xn, cosb, sinb,
            Wgate + (size_t)l * 128, ve + (size_t)l * TT * KVD, hasve, qn, kn, vrow);

        vtrans_k<<<dim3(32, 8), 256, 0, stream>>>(vrow, vt);

        attn_k<<<dim3(32, 8), 256, 0, stream>>>(qn, kn, vt, yb, seqlens, isS);

        gemm2<0><<<dim3(16, 8, 2), 256, 0, stream>>>(yb, Bo + (size_t)l * 1024 * 1024,
                                                     part, nullptr, 1024, 512, 1024);
        reduce_add_k<<<2048, 256, 0, stream>>>(h, part, 2);

        rmsnorm_k<<<TT, 256, 0, stream>>>(h, xn);

        gemm2<2><<<dim3(16, 32, 1), 256, 0, stream>>>(xn, Bfc + (size_t)l * 4096 * 1024,
                                                      nullptr, mb, 1024, 1024, 4096);

        gemm2<0><<<dim3(16, 8, 4), 256, 0, stream>>>(mb, Bproj + (size_t)l * 1024 * 4096,
                                                     part, nullptr, 4096, 1024, 1024);
        reduce_add_k<<<2048, 256, 0, stream>>>(h, part, 4);
    }
}

// Round 4
// 1610.845 us; speedup vs baseline: 2.5704x; 1.0013x over previous
//
#include <hip/hip_runtime.h>
#include <hip/hip_bf16.h>
#include <cstdint>
#include <cstddef>

#define TT     2048
#define DMODEL 1024
#define NHQ    8
#define HD     128
#define KVD    512
#define WIN    384
#define EPSF   1.1920929e-07f
#define SCALE  0.12f

typedef __attribute__((ext_vector_type(8))) short bf16x8;
typedef __attribute__((ext_vector_type(4))) float f32x4;

#define WAITV(N)  asm volatile("s_waitcnt vmcnt(" #N ")" ::: "memory")
#define WAITLGKM  asm volatile("s_waitcnt lgkmcnt(0)" ::: "memory")

__device__ __forceinline__ float b2f(unsigned short u) {
    unsigned int i = ((unsigned int)u) << 16; float f; __builtin_memcpy(&f, &i, 4); return f;
}
__device__ __forceinline__ unsigned short f2b(float f) {
    unsigned int i; __builtin_memcpy(&i, &f, 4);
    unsigned int r = (i + 0x7fffu + ((i >> 16) & 1u)) >> 16;
    return (unsigned short)r;
}

__device__ __forceinline__ void gl_lds16(const unsigned short* g, unsigned short* l) {
    __builtin_amdgcn_global_load_lds(
        (const __attribute__((address_space(1))) unsigned int*)g,
        (__attribute__((address_space(3))) unsigned int*)l, 16, 0, 0);
}

// ---------------------------------------------------------------------------
// Weight convert+transpose for ALL layers: W f32 [K][N] -> Wt bf16 [N][K].
// grid = (2816, 8); blockIdx.y = layer. Conflict-free LDS (f32 [64][65]),
// coalesced reads and writes.
// ---------------------------------------------------------------------------
__global__ __launch_bounds__(256)
void convT_k(const float* __restrict__ Wq, const float* __restrict__ Wk,
             const float* __restrict__ Wv, const float* __restrict__ Wo,
             const float* __restrict__ Wfc, const float* __restrict__ Wproj,
             unsigned short* __restrict__ Bqkv, unsigned short* __restrict__ Bo,
             unsigned short* __restrict__ Bfc, unsigned short* __restrict__ Bproj)
{
    __shared__ float lt[64][65];
    const int bid = blockIdx.x, tid = threadIdx.x, l = blockIdx.y;

    const float* W; unsigned short* Wt; int K, N, t, nbase;
    if (bid < 256)        { W = Wq    + (size_t)l * 1024 * 1024; Wt = Bqkv  + (size_t)l * 2048 * 1024; K = 1024; N = 1024; t = bid;        nbase = 0;    }
    else if (bid < 384)   { W = Wk    + (size_t)l * 1024 * 512;  Wt = Bqkv  + (size_t)l * 2048 * 1024; K = 1024; N = 512;  t = bid - 256;  nbase = 1024; }
    else if (bid < 512)   { W = Wv    + (size_t)l * 1024 * 512;  Wt = Bqkv  + (size_t)l * 2048 * 1024; K = 1024; N = 512;  t = bid - 384;  nbase = 1536; }
    else if (bid < 768)   { W = Wo    + (size_t)l * 1024 * 1024; Wt = Bo    + (size_t)l * 1024 * 1024; K = 1024; N = 1024; t = bid - 512;  nbase = 0;    }
    else if (bid < 1792)  { W = Wfc   + (size_t)l * 1024 * 4096; Wt = Bfc   + (size_t)l * 4096 * 1024; K = 1024; N = 4096; t = bid - 768;  nbase = 0;    }
    else                  { W = Wproj + (size_t)l * 4096 * 1024; Wt = Bproj + (size_t)l * 1024 * 4096; K = 4096; N = 1024; t = bid - 1792; nbase = 0;    }

    const int ktiles = K >> 6;
    const int k0 = (t % ktiles) * 64, n0 = (t / ktiles) * 64;

    // read 64(k) x 64(n) f32 tile, coalesced; LDS [k][n] with +1 pad
    #pragma unroll
    for (int i = 0; i < 4; ++i) {
        int row = (tid >> 4) + i * 16;          // k
        int col = (tid & 15) * 4;               // n
        float4 v = *(const float4*)(W + (size_t)(k0 + row) * N + n0 + col);
        lt[row][col + 0] = v.x;
        lt[row][col + 1] = v.y;
        lt[row][col + 2] = v.z;
        lt[row][col + 3] = v.w;
    }
    __syncthreads();
    // write bf16 [n][k], 16B per lane, 8 lanes per n-row (coalesced 128B)
    #pragma unroll
    for (int i = 0; i < 2; ++i) {
        int idx = tid + i * 256;
        int n = idx >> 3, kc = (idx & 7) * 8;
        unsigned short o[8];
        #pragma unroll
        for (int j = 0; j < 8; ++j) o[j] = f2b(lt[kc + j][n]);
        *(uint4*)(Wt + (size_t)(nbase + n0 + n) * K + k0 + kc) = *(const uint4*)o;
    }
}

// ---------------------------------------------------------------------------
// 4-deep pipelined GEMM: C = A(bf16 [M][K]) * Bt(bf16 [Ntot][K])^T
// 128x128 tile, BK=32, 4 LDS buffers, counted vmcnt (never drains to 0 in
// steady state), raw s_barrier. EPI 0: f32 store at Cf + z*TT*Ntot;
// EPI 2: relu^2 -> bf16 at Cb.
// ---------------------------------------------------------------------------
template<int EPI>
__global__ __launch_bounds__(256)
void gemm2(const unsigned short* __restrict__ A, const unsigned short* __restrict__ Bt,
           float* __restrict__ Cf, unsigned short* __restrict__ Cb,
           int K, int ksplit, int Ntot)
{
    __shared__ unsigned short As[4 * 128 * 32];
    __shared__ unsigned short Bs[4 * 128 * 32];
    const int BUF = 128 * 32;
    const int tid = threadIdx.x, lane = tid & 63, wv = tid >> 6;
    const int m0 = blockIdx.x * 128, n0 = blockIdx.y * 128;
    const int kbeg = blockIdx.z * ksplit;
    const int NT = ksplit >> 5;

    const int wr = (wv >> 1) * 64, wc = (wv & 1) * 64;
    const int l15 = lane & 15, lk = (lane >> 4) * 8;
    const int srow = lane >> 2, scol = (lane & 3) * 8;

    const unsigned short* gA0 = A  + (size_t)(m0 + wv * 32 + srow) * K + scol;
    const unsigned short* gB0 = Bt + (size_t)(n0 + wv * 32 + srow) * K + scol;
    unsigned short* lA0 = As + (wv * 32) * 32;
    unsigned short* lB0 = Bs + (wv * 32) * 32;

    auto stage = [&](int t) {
        const int k = kbeg + (t << 5);
        unsigned short* la = lA0 + (t & 3) * BUF;
        unsigned short* lb = lB0 + (t & 3) * BUF;
        gl_lds16(gA0 + k,          la);
        gl_lds16(gA0 + k + 16 * K, la + 16 * 32);
        gl_lds16(gB0 + k,          lb);
        gl_lds16(gB0 + k + 16 * K, lb + 16 * 32);
    };

    f32x4 acc[4][4] = {};

    stage(0);
    if (NT > 1) stage(1);
    if (NT > 2) stage(2);

    for (int t = 0; t < NT; ++t) {
        WAITLGKM;
        if (t + 2 < NT)      { WAITV(8); }   // ≤12 outstanding; oldest 4 (tile t) done
        else if (t + 1 < NT) { WAITV(4); }
        else                 { WAITV(0); }
        __builtin_amdgcn_s_barrier();        // tile t globally in LDS; buf(t-1) readers done
        if (t + 3 < NT) stage(t + 3);        // overwrite buf (t-1)

        const unsigned short* Ac = As + (t & 3) * BUF;
        const unsigned short* Bc = Bs + (t & 3) * BUF;
        bf16x8 af[4], bfv[4];
        #pragma unroll
        for (int mi = 0; mi < 4; ++mi) af[mi]  = *(const bf16x8*)(Ac + (wr + mi * 16 + l15) * 32 + lk);
        #pragma unroll
        for (int ni = 0; ni < 4; ++ni) bfv[ni] = *(const bf16x8*)(Bc + (wc + ni * 16 + l15) * 32 + lk);
        #pragma unroll
        for (int mi = 0; mi < 4; ++mi)
            #pragma unroll
            for (int ni = 0; ni < 4; ++ni)
                acc[mi][ni] = __builtin_amdgcn_mfma_f32_16x16x32_bf16(af[mi], bfv[ni], acc[mi][ni], 0, 0, 0);
    }

    const int lr4 = (lane >> 4) * 4;
    float* Cz = Cf + (size_t)blockIdx.z * TT * Ntot;
    #pragma unroll
    for (int mi = 0; mi < 4; ++mi)
        #pragma unroll
        for (int ni = 0; ni < 4; ++ni)
            #pragma unroll
            for (int r = 0; r < 4; ++r) {
                int row = m0 + wr + mi * 16 + lr4 + r;
                int col = n0 + wc + ni * 16 + l15;
                size_t idx = (size_t)row * Ntot + col;
                float v = acc[mi][ni][r];
                if (EPI == 0) Cz[idx] = v;
                else {
                    float z = v > 0.f ? v * v : 0.f;
                    Cb[idx] = f2b(z);
                }
            }
}

// ---------------------------------------------------------------------------
__global__ __launch_bounds__(256)
void reduce_add_k(float* __restrict__ h, const float* __restrict__ part, int nz)
{
    const int i = blockIdx.x * 256 + threadIdx.x;
    float4 a = ((const float4*)part)[i];
    for (int z = 1; z < nz; ++z) {
        float4 p = ((const float4*)part)[i + (size_t)z * (TT * DMODEL / 4)];
        a.x += p.x; a.y += p.y; a.z += p.z; a.w += p.w;
    }
    float4 hv = ((float4*)h)[i];
    hv.x += a.x; hv.y += a.y; hv.z += a.z; hv.w += a.w;
    ((float4*)h)[i] = hv;
}

// ---------------------------------------------------------------------------
__global__ __launch_bounds__(256)
void rmsnorm_k(const float* __restrict__ h, unsigned short* __restrict__ xn)
{
    const int t = blockIdx.x, tid = threadIdx.x;
    float4 v = *(const float4*)(h + (size_t)t * DMODEL + tid * 4);
    float ss = v.x*v.x + v.y*v.y + v.z*v.z + v.w*v.w;
    #pragma unroll
    for (int m = 1; m < 64; m <<= 1) ss += __shfl_xor(ss, m);
    __shared__ float red[4];
    if ((tid & 63) == 0) red[tid >> 6] = ss;
    __syncthreads();
    float tot = red[0] + red[1] + red[2] + red[3];
    float rs = rsqrtf(tot * (1.f / DMODEL) + EPSF);
    unsigned short o[4] = { f2b(v.x*rs), f2b(v.y*rs), f2b(v.z*rs), f2b(v.w*rs) };
    *(ushort4*)(xn + (size_t)t * DMODEL + tid * 4) = *(const ushort4*)o;
}

// ---------------------------------------------------------------------------
// Post-QKV: rotary + head-RMSNorm on q,k (->bf16); ve-gate + bf16 on v (row-major)
// ---------------------------------------------------------------------------
__global__ __launch_bounds__(256)
void post_qkv_k(const float* __restrict__ qkv, const unsigned short* __restrict__ xn,
                const float* __restrict__ cosb, const float* __restrict__ sinb,
                const float* __restrict__ Wgate, const float* __restrict__ vel, int hasve,
                unsigned short* __restrict__ qn, unsigned short* __restrict__ kn,
                unsigned short* __restrict__ vrow)
{
    const int t = blockIdx.x, tid = threadIdx.x;
    __shared__ float cs[64], sn[64], gate[4];
    if (tid < 64) { cs[tid] = cosb[t * 64 + tid]; sn[tid] = sinb[t * 64 + tid]; }
    if (hasve && tid >= 64 && tid < 68) {
        int g = tid - 64; float a = 0.f;
        for (int c = 0; c < 32; ++c) a += b2f(xn[(size_t)t * DMODEL + c]) * Wgate[c * 4 + g];
        gate[g] = 2.f / (1.f + __expf(-a));
    }
    __syncthreads();
    if (tid < 96) {
        const int hid = tid >> 3, sub = tid & 7;
        const float* src; unsigned short* dst;
        if (hid < 8) { src = qkv + (size_t)t * 2048 + hid * 128;              dst = qn + (size_t)t * 1024 + hid * 128; }
        else         { src = qkv + (size_t)t * 2048 + 1024 + (hid - 8) * 128; dst = kn + (size_t)t * 512 + (hid - 8) * 128; }
        float o1[8], o2[8], ssum = 0.f;
        #pragma unroll
        for (int j = 0; j < 8; ++j) {
            int jj = sub * 8 + j;
            float x1 = src[jj], x2 = src[jj + 64];
            float c = cs[jj], s = sn[jj];
            o1[j] = x1 * c + x2 * s;
            o2[j] = -x1 * s + x2 * c;
            ssum += o1[j]*o1[j] + o2[j]*o2[j];
        }
        ssum += __shfl_xor(ssum, 1); ssum += __shfl_xor(ssum, 2); ssum += __shfl_xor(ssum, 4);
        float rs = rsqrtf(ssum * (1.f / HD) + EPSF);
        #pragma unroll
        for (int j = 0; j < 8; ++j) {
            int jj = sub * 8 + j;
            dst[jj]      = f2b(o1[j] * rs);
            dst[jj + 64] = f2b(o2[j] * rs);
        }
    }
    {
        int d0 = tid * 2;
        #pragma unroll
        for (int j = 0; j < 2; ++j) {
            int d = d0 + j;
            float vv = qkv[(size_t)t * 2048 + 1536 + d];
            if (hasve) vv += gate[d >> 7] * vel[(size_t)t * KVD + d];
            vrow[(size_t)t * KVD + d] = f2b(vv);
        }
    }
}

// ---------------------------------------------------------------------------
// vrow [T][KVD] -> vt [KVD][T]  (64x64 LDS tile transpose)
// ---------------------------------------------------------------------------
__global__ __launch_bounds__(256)
void vtrans_k(const unsigned short* __restrict__ vrow, unsigned short* __restrict__ vt)
{
    __shared__ unsigned short lt[64][72];
    const int t0 = blockIdx.x * 64, c0 = blockIdx.y * 64, tid = threadIdx.x;
    #pragma unroll
    for (int i = 0; i < 2; ++i) {
        int r = (tid >> 3) + i * 32;
        int c = (tid & 7) * 8;
        bf16x8 v = *(const bf16x8*)(vrow + (size_t)(t0 + r) * KVD + c0 + c);
        #pragma unroll
        for (int j = 0; j < 8; ++j) lt[c + j][r] = ((unsigned short*)&v)[j];
    }
    __syncthreads();
    #pragma unroll
    for (int i = 0; i < 2; ++i) {
        int r = (tid >> 3) + i * 32;
        int c = (tid & 7) * 8;
        *(bf16x8*)(vt + (size_t)(c0 + r) * TT + t0 + c) = *(const bf16x8*)(&lt[r][c]);
    }
}

// ---------------------------------------------------------------------------
// Flash attention: 1 wave per 16 q-rows per head; SBLK=32; online softmax.
// ---------------------------------------------------------------------------
__global__ __launch_bounds__(256)
void attn_k(const unsigned short* __restrict__ qn, const unsigned short* __restrict__ kn,
            const unsigned short* __restrict__ vt, unsigned short* __restrict__ y,
            const int* __restrict__ seqlens, int isS)
{
    __shared__ unsigned short Plds[4][16][40];
    const int tid = threadIdx.x, w = tid >> 6, lane = tid & 63;
    const int h = blockIdx.y, hkv = h >> 1;
    const int qr = (blockIdx.x * 4 + w) * 16;
    const int s1 = seqlens[1], s2 = seqlens[2], s3 = seqlens[3];
    const int l15 = lane & 15, lhi = lane >> 4;

    bf16x8 qf[4];
    #pragma unroll
    for (int kk = 0; kk < 4; ++kk)
        qf[kk] = *(const bf16x8*)(qn + (size_t)(qr + l15) * 1024 + h * HD + kk * 32 + lhi * 8);

    int drow[4];
    #pragma unroll
    for (int r = 0; r < 4; ++r) {
        int row = qr + lhi * 4 + r;
        drow[r] = (row >= s1) + (row >= s2) + (row >= s3);
    }
    int dq = (qr >= s1) + (qr >= s2) + (qr >= s3);
    int dstart = dq == 0 ? 0 : (dq == 1 ? s1 : (dq == 2 ? s2 : s3));
    int smin = dstart;
    if (isS) { int wlo = qr - WIN; if (wlo > smin) smin = wlo; }
    if (smin < 0) smin = 0;
    const int smax = qr + 16;

    f32x4 acc[8] = {};
    float mrow[4] = { -1e30f, -1e30f, -1e30f, -1e30f };
    float lrow[4] = { 0.f, 0.f, 0.f, 0.f };

    for (int s0 = smin & ~31; s0 < smax; s0 += 32) {
        float sv[2][4];
        #pragma unroll
        for (int nb = 0; nb < 2; ++nb) {
            f32x4 S = {};
            int scol = s0 + nb * 16 + l15;
            int scl = scol < TT ? scol : TT - 1;
            #pragma unroll
            for (int kk = 0; kk < 4; ++kk) {
                bf16x8 kf = *(const bf16x8*)(kn + (size_t)scl * KVD + hkv * HD + kk * 32 + lhi * 8);
                S = __builtin_amdgcn_mfma_f32_16x16x32_bf16(qf[kk], kf, S, 0, 0, 0);
            }
            int dcol = (scol >= s1) + (scol >= s2) + (scol >= s3);
            #pragma unroll
            for (int r = 0; r < 4; ++r) {
                int row = qr + lhi * 4 + r;
                bool valid = (scol <= row) && (dcol == drow[r]) && (!isS || (row - scol) <= WIN);
                sv[nb][r] = valid ? S[r] * SCALE : -1e30f;
            }
        }
        #pragma unroll
        for (int r = 0; r < 4; ++r) {
            float pm = fmaxf(sv[0][r], sv[1][r]);
            pm = fmaxf(pm, __shfl_xor(pm, 1));
            pm = fmaxf(pm, __shfl_xor(pm, 2));
            pm = fmaxf(pm, __shfl_xor(pm, 4));
            pm = fmaxf(pm, __shfl_xor(pm, 8));
            float mnew = fmaxf(mrow[r], pm);
            float scl2 = __expf(mrow[r] - mnew);
            float p0 = __expf(sv[0][r] - mnew);
            float p1 = __expf(sv[1][r] - mnew);
            float ps = p0 + p1;
            ps += __shfl_xor(ps, 1); ps += __shfl_xor(ps, 2);
            ps += __shfl_xor(ps, 4); ps += __shfl_xor(ps, 8);
            lrow[r] = lrow[r] * scl2 + ps;
            mrow[r] = mnew;
            #pragma unroll
            for (int nb = 0; nb < 8; ++nb) acc[nb][r] *= scl2;
            Plds[w][lhi * 4 + r][l15]      = f2b(p0);
            Plds[w][lhi * 4 + r][16 + l15] = f2b(p1);
        }
        bf16x8 pf = *(const bf16x8*)(&Plds[w][l15][lhi * 8]);
        #pragma unroll
        for (int nb = 0; nb < 8; ++nb) {
            bf16x8 vf = *(const bf16x8*)(vt + (size_t)(hkv * HD + nb * 16 + l15) * TT + s0 + lhi * 8);
            acc[nb] = __builtin_amdgcn_mfma_f32_16x16x32_bf16(pf, vf, acc[nb], 0, 0, 0);
        }
    }
    #pragma unroll
    for (int r = 0; r < 4; ++r) {
        float inv = 1.f / lrow[r];
        int row = qr + lhi * 4 + r;
        #pragma unroll
        for (int nb = 0; nb < 8; ++nb)
            y[(size_t)row * 1024 + h * HD + nb * 16 + l15] = f2b(acc[nb][r] * inv);
    }
}

// ---------------------------------------------------------------------------
extern "C" void kernel_launch(void* const* d_in, const int* in_sizes, int n_in,
                              void* d_out, int out_size, void* d_ws, size_t ws_size,
                              hipStream_t stream)
{
    const float* x       = (const float*)d_in[0];
    const float* ve      = (const float*)d_in[1];
    const float* Wq      = (const float*)d_in[2];
    const float* Wk      = (const float*)d_in[3];
    const float* Wv      = (const float*)d_in[4];
    const float* Wo      = (const float*)d_in[5];
    const float* Wgate   = (const float*)d_in[6];
    const float* Wfc     = (const float*)d_in[7];
    const float* Wproj   = (const float*)d_in[8];
    const float* cosb    = (const float*)d_in[9];
    const float* sinb    = (const float*)d_in[10];
    const int*   seqlens = (const int*)d_in[11];

    float* h = (float*)d_out;
    char* ws = (char*)d_ws;
    unsigned short* xn    = (unsigned short*)(ws);                  // 4 MB
    float*          qkvf  = (float*)(ws + (4ull << 20));            // 16 MB
    unsigned short* qn    = (unsigned short*)(ws + (20ull << 20));  // 4 MB
    unsigned short* kn    = (unsigned short*)(ws + (24ull << 20));  // 2 MB
    unsigned short* vrow  = (unsigned short*)(ws + (26ull << 20));  // 2 MB
    unsigned short* vt    = (unsigned short*)(ws + (28ull << 20));  // 2 MB
    unsigned short* yb    = (unsigned short*)(ws + (30ull << 20));  // 4 MB
    unsigned short* mb    = (unsigned short*)(ws + (34ull << 20));  // 16 MB
    float*          part  = (float*)(ws + (50ull << 20));           // 32 MB
    unsigned short* Bqkv  = (unsigned short*)(ws + (82ull << 20));  // 32 MB (8 layers)
    unsigned short* Bo    = (unsigned short*)(ws + (114ull << 20)); // 16 MB
    unsigned short* Bfc   = (unsigned short*)(ws + (130ull << 20)); // 64 MB
    unsigned short* Bproj = (unsigned short*)(ws + (194ull << 20)); // 64 MB -> 258 MB

    hipMemcpyAsync(h, x, (size_t)TT * DMODEL * sizeof(float), hipMemcpyDeviceToDevice, stream);

    convT_k<<<dim3(2816, 8), 256, 0, stream>>>(Wq, Wk, Wv, Wo, Wfc, Wproj,
                                               Bqkv, Bo, Bfc, Bproj);

    for (int l = 0; l < 8; ++l) {
        int hasve = (l % 2) == 1;
        int isS   = (l % 4) != 3;

        rmsnorm_k<<<TT, 256, 0, stream>>>(h, xn);

        gemm2<0><<<dim3(16, 16, 1), 256, 0, stream>>>(xn, Bqkv + (size_t)l * 2048 * 1024,
                                                      qkvf, nullptr, 1024, 1024, 2048);

        post_qkv_k<<<TT, 256, 0, stream>>>(qkvf, xn, cosb, sinb,
            Wgate + (size_t)l * 128, ve + (size_t)l * TT * KVD, hasve, qn, kn, vrow);

        vtrans_k<<<dim3(32, 8), 256, 0, stream>>>(vrow, vt);

        attn_k<<<dim3(32, 8), 256, 0, stream>>>(qn, kn, vt, yb, seqlens, isS);

        gemm2<0><<<dim3(16, 8, 2), 256, 0, stream>>>(yb, Bo + (size_t)l * 1024 * 1024,
                                                     part, nullptr, 1024, 512, 1024);
        reduce_add_k<<<2048, 256, 0, stream>>>(h, part, 2);

        rmsnorm_k<<<TT, 256, 0, stream>>>(h, xn);

        gemm2<2><<<dim3(16, 32, 1), 256, 0, stream>>>(xn, Bfc + (size_t)l * 4096 * 1024,
                                                      nullptr, mb, 1024, 1024, 4096);

        gemm2<0><<<dim3(16, 8, 4), 256, 0, stream>>>(mb, Bproj + (size_t)l * 1024 * 4096,
                                                     part, nullptr, 4096, 1024, 1024);
        reduce_add_k<<<2048, 256, 0, stream>>>(h, part, 4);
    }
}